// Round 4
// baseline (525.165 us; speedup 1.0000x reference)
//
#include <hip/hip_runtime.h>
#include <math.h>

#define NTOK   32768
#define DDIM   2048
#define NEXP   64
#define TOKB   64              // tokens per block
#define BLOCK  512             // 8 waves
#define NTI    2               // tokens per lane (per 16-lane expert group)
#define RD     128             // d-rows per LDS round
#define NR     (DDIM / RD)     // 16 rounds
#define JB     (RD / 16)       // 8 jb per round, 16 d each
#define BUFSZ  (RD * NEXP)     // floats per W buffer (8192 = 32 KB)

union Smem {
    float wbuf[2 * BUFSZ];          // 64 KB: double-buffered W chunk
    float logit[TOKB][NEXP + 1];    // epilogue gather (stride 65, conflict-free)
};

#define XGET(v, dd) ((dd)==0 ? (v).x : (dd)==1 ? (v).y : (dd)==2 ? (v).z : (v).w)

// async global->LDS, 16B per lane, dest = wave-uniform base + lane*16
#define GLD16(gp, lp) __builtin_amdgcn_global_load_lds(                      \
    (const __attribute__((address_space(1))) void*)(gp),                     \
    (__attribute__((address_space(3))) void*)(lp), 16, 0, 0)

// end-of-round fence: LDS reads of current buffer drained (lgkmcnt); vmem
// drained down to the 16 newest (in-order retirement => this round's 4 W
// global_load_lds, issued FIRST in the round, are retired; jb6/jb7's 16
// x-ring prefetches for the next round legally stay in flight), then barrier.
#define RBAR() {                                             \
    asm volatile("s_waitcnt lgkmcnt(0)" ::: "memory");       \
    asm volatile("s_waitcnt vmcnt(16)" ::: "memory");        \
    __builtin_amdgcn_s_barrier();                            \
    asm volatile("" ::: "memory"); }

// one j4 step (4 d-rows): W slice from LDS, x from ring regs, 32 FMAs,
// then reload the ring slot 2 jb (32 d) ahead. Chain order per
// (token,expert): ascending d, fmaf — bitwise-identical to the validated
// kernel.
#define STEP(p, XP, PFX) {                                                   \
    float4 wc[4];                                                            \
    _Pragma("unroll")                                                        \
    for (int dd = 0; dd < 4; ++dd)                                           \
        wc[dd] = *(const float4*)(wj + ((p) * 4 + dd) * NEXP);               \
    _Pragma("unroll")                                                        \
    for (int dd = 0; dd < 4; ++dd) {                                         \
        _Pragma("unroll")                                                    \
        for (int i = 0; i < NTI; ++i) {                                      \
            const float xv = XGET(XP[i], dd);                                \
            a2[i][0] = fmaf(xv, wc[dd].x, a2[i][0]);                         \
            a2[i][1] = fmaf(xv, wc[dd].y, a2[i][1]);                         \
            a2[i][2] = fmaf(xv, wc[dd].z, a2[i][2]);                         \
            a2[i][3] = fmaf(xv, wc[dd].w, a2[i][3]);                         \
        }                                                                    \
    }                                                                        \
    if (PFX) {                                                               \
        XP[0] = *(const float4*)(xr + (p) * 4);                              \
        XP[1] = *(const float4*)(xr + DDIM + (p) * 4);                       \
    } }

__global__ __launch_bounds__(BLOCK, 4)
void router_kernel(const float* __restrict__ x, const float* __restrict__ wde,
                   float* __restrict__ out) {
    __shared__ Smem sm;
    float* smw = sm.wbuf;

    const int tid  = threadIdx.x;
    const int lane = tid & 63;
    const int w    = tid >> 6;          // wave 0..7
    const int g    = lane >> 4;         // token group 0..3
    const int el   = lane & 15;         // expert-quad: experts el*4..el*4+3
    const int tl0  = w * 8 + g * NTI;   // lane's first local token
    const int tok0 = blockIdx.x * TOKB;

    // stage W round chunk via async direct-to-LDS: 32 KB = 32 wave-instrs,
    // 4 per wave; chunk c = s*8 + w covers bytes [c*1024, c*1024+1024)
    auto stage = [&](int r, int bofs) {
        const char* gsrc = (const char*)wde + (size_t)r * (RD * NEXP * 4);
        char* lbase = (char*)(smw + bofs);
        #pragma unroll
        for (int s = 0; s < 4; ++s) {
            const int c = s * 8 + w;
            GLD16(gsrc + c * 1024 + lane * 16, lbase + c * 1024);
        }
    };

    // quarter accumulators: a2 = running quarter, s01 = q0+q1, s23 = q2+q3
    float a2[NTI][4], s01[NTI][4], s23[NTI][4];
    #pragma unroll
    for (int i = 0; i < NTI; ++i)
        #pragma unroll
        for (int e = 0; e < 4; ++e) { a2[i][e] = 0.0f; s01[i][e] = 0.0f; s23[i][e] = 0.0f; }

    // ---- prologue: async-stage W round 0 (oldest in vmem queue), then the
    // 8-slot x ring: XA* = jb0 (d 0..15), XB* = jb1 (d 16..31) ----
    stage(0, 0);
    __builtin_amdgcn_sched_barrier(0);   // keep gloads oldest

    const float* xq = x + (size_t)(tok0 + tl0) * DDIM;
    float4 XA0[NTI], XA1[NTI], XA2[NTI], XA3[NTI];
    float4 XB0[NTI], XB1[NTI], XB2[NTI], XB3[NTI];
    #pragma unroll
    for (int i = 0; i < NTI; ++i) {
        const float* xi = xq + (size_t)i * DDIM;
        XA0[i] = *(const float4*)(xi + 0);
        XA1[i] = *(const float4*)(xi + 4);
        XA2[i] = *(const float4*)(xi + 8);
        XA3[i] = *(const float4*)(xi + 12);
        XB0[i] = *(const float4*)(xi + 16);
        XB1[i] = *(const float4*)(xi + 20);
        XB2[i] = *(const float4*)(xi + 24);
        XB3[i] = *(const float4*)(xi + 28);
    }
    RBAR();   // vmcnt(16): 4 W gloads retired, 16 x preloads stay in flight

    // ---- main loop: 16 rounds of 128 d, one barrier per round ----
    int bo = 0;
    for (int r = 0; r < NR; ++r) {
        const bool lastr = (r == NR - 1);
        if (!lastr) {
            stage(r + 1, bo ^ BUFSZ);    // async into the other buffer
            __builtin_amdgcn_sched_barrier(0);
        }
        const float* wl = smw + bo + el * 4;
        #pragma unroll
        for (int jb = 0; jb < JB; ++jb) {
            const float* wj = wl + jb * 16 * NEXP;
            const float* xr = xq + jb * 16 + 32;           // 2 jb ahead
            const bool pf = (!lastr) || (jb < JB - 2);     // no OOB at the end
            if ((jb & 1) == 0) {
                STEP(0, XA0, pf)
                STEP(1, XA1, pf)
                STEP(2, XA2, pf)
                STEP(3, XA3, pf)
            } else {
                STEP(0, XB0, pf)
                STEP(1, XB1, pf)
                STEP(2, XB2, pf)
                STEP(3, XB3, pf)
            }
        }
        RBAR();
        bo ^= BUFSZ;
        xq += RD;
        if ((r & 3) == 3) {                 // quarter boundary: fold, re-zero
            const int q = r >> 2;
            #pragma unroll
            for (int i = 0; i < NTI; ++i)
                #pragma unroll
                for (int e = 0; e < 4; ++e) {
                    if (q == 0)      s01[i][e]  = a2[i][e];
                    else if (q == 1) s01[i][e] += a2[i][e];
                    else if (q == 2) s23[i][e]  = a2[i][e];
                    else             s23[i][e] += a2[i][e];
                    a2[i][e] = 0.0f;
                }
        }
    }

    // combine quarters exactly like the validated kernel: (q0+q1)+(q2+q3)
    #pragma unroll
    for (int i = 0; i < NTI; ++i)
        #pragma unroll
        for (int e = 0; e < 4; ++e)
            sm.logit[tl0 + i][el * 4 + e] = s01[i][e] + s23[i][e];
    __syncthreads();

    if (tid < 64) {
        const int tok = tok0 + tid;
        float lg[NEXP];
        #pragma unroll
        for (int e = 0; e < NEXP; ++e) lg[e] = sm.logit[tid][e];

        // softmax over 64 experts (fp32, max-subtracted)
        float m = lg[0];
        #pragma unroll
        for (int e = 1; e < NEXP; ++e) m = fmaxf(m, lg[e]);
        float s = 0.0f;
        #pragma unroll
        for (int e = 0; e < NEXP; ++e) { lg[e] = expf(lg[e] - m); s += lg[e]; }

        // top-8, strict '>' keeps lowest index on ties (lax.top_k semantics)
        unsigned long long chosen = 0ull;
        float wv[8], wi[8];
        #pragma unroll
        for (int k = 0; k < 8; ++k) {
            float best = -1.0f; int bi = 0;
            #pragma unroll
            for (int e = 0; e < NEXP; ++e) {
                bool ok = (((chosen >> e) & 1ull) == 0ull) && (lg[e] > best);
                best = ok ? lg[e] : best;
                bi   = ok ? e : bi;
            }
            chosen |= (1ull << bi);
            wv[k] = best;
            wi[k] = (float)bi;
        }

        // second softmax over the 8 selected gating probabilities
        float p0 = wv[0] / s;
        float e2[8]; float s2 = 0.0f;
        #pragma unroll
        for (int k = 0; k < 8; ++k) { e2[k] = expf(wv[k] / s - p0); s2 += e2[k]; }

        float4* ow = (float4*)(out + (size_t)tok * 8);
        ow[0] = make_float4(e2[0]/s2, e2[1]/s2, e2[2]/s2, e2[3]/s2);
        ow[1] = make_float4(e2[4]/s2, e2[5]/s2, e2[6]/s2, e2[7]/s2);
        float4* oi = (float4*)(out + (size_t)NTOK * 8 + (size_t)tok * 8);
        oi[0] = make_float4(wi[0], wi[1], wi[2], wi[3]);
        oi[1] = make_float4(wi[4], wi[5], wi[6], wi[7]);
    }
}

extern "C" void kernel_launch(void* const* d_in, const int* in_sizes, int n_in,
                              void* d_out, int out_size, void* d_ws, size_t ws_size,
                              hipStream_t stream) {
    const float* x   = (const float*)d_in[0];
    const float* wde = (const float*)d_in[1];
    float* out       = (float*)d_out;
    router_kernel<<<dim3(NTOK / TOKB), dim3(BLOCK), 0, stream>>>(x, wde, out);
}

// Round 5
// 416.132 us; speedup vs baseline: 1.2620x; 1.2620x over previous
//
#include <hip/hip_runtime.h>
#include <math.h>

#define NTOK   32768
#define DDIM   2048
#define NEXP   64
#define TOKB   64              // tokens per block
#define BLOCK  512             // 8 waves
#define NTI    2               // tokens per lane (per 16-lane expert group)
#define RD     64              // d-rows per round
#define NR     (DDIM / RD)     // 32 rounds
#define JB     (RD / 16)       // 4 jb per round, 16 d each
#define CHF    (RD * NEXP)     // 4096 floats = 16 KB per chunk (W and x alike)

union Smem {
    float buf[4 * CHF];             // [0,2*CHF): W dbuf | [2*CHF,4*CHF): x dbuf (64 KB)
    float logit[TOKB][NEXP + 1];    // epilogue gather (stride 65, conflict-free)
};

#define XGET(v, dd) ((dd)==0 ? (v).x : (dd)==1 ? (v).y : (dd)==2 ? (v).z : (v).w)

// async global->LDS, 16B per lane, dest = wave-uniform base + lane*16
#define GLD16(gp, lp) __builtin_amdgcn_global_load_lds(                      \
    (const __attribute__((address_space(1))) void*)(gp),                     \
    (__attribute__((address_space(3))) void*)(lp), 16, 0, 0)

// round fence: own LDS reads drained, own stage gloads (issued a full round
// earlier => already landed in steady state) retired, then barrier. vmcnt(0)
// is near-free here because nothing vmem-side is issued late in the round.
#define RBAR() {                                             \
    asm volatile("s_waitcnt lgkmcnt(0)" ::: "memory");       \
    asm volatile("s_waitcnt vmcnt(0)" ::: "memory");         \
    __builtin_amdgcn_s_barrier();                            \
    asm volatile("" ::: "memory"); }

// one j4 step (4 d-rows): W slice + x (XOR-deswizzled slot) from LDS, 32 FMAs.
// Chain order per (token,expert): ascending d, fmaf — bitwise-identical to the
// validated kernel.
#define STEP(p) {                                                            \
    float4 wc0 = *(const float4*)(wj + ((p) * 4 + 0) * NEXP);                \
    float4 wc1 = *(const float4*)(wj + ((p) * 4 + 1) * NEXP);                \
    float4 wc2 = *(const float4*)(wj + ((p) * 4 + 2) * NEXP);                \
    float4 wc3 = *(const float4*)(wj + ((p) * 4 + 3) * NEXP);                \
    float4 xq0 = *(const float4*)(xj0 + (((p) ^ g) << 2));                   \
    float4 xq1 = *(const float4*)(xj1 + (((p) ^ g) << 2));                   \
    _Pragma("unroll")                                                        \
    for (int dd = 0; dd < 4; ++dd) {                                         \
        const float4 wcd = (dd==0) ? wc0 : (dd==1) ? wc1 : (dd==2) ? wc2 : wc3; \
        {   const float xv = XGET(xq0, dd);                                  \
            a2[0][0] = fmaf(xv, wcd.x, a2[0][0]);                            \
            a2[0][1] = fmaf(xv, wcd.y, a2[0][1]);                            \
            a2[0][2] = fmaf(xv, wcd.z, a2[0][2]);                            \
            a2[0][3] = fmaf(xv, wcd.w, a2[0][3]); }                          \
        {   const float xv = XGET(xq1, dd);                                  \
            a2[1][0] = fmaf(xv, wcd.x, a2[1][0]);                            \
            a2[1][1] = fmaf(xv, wcd.y, a2[1][1]);                            \
            a2[1][2] = fmaf(xv, wcd.z, a2[1][2]);                            \
            a2[1][3] = fmaf(xv, wcd.w, a2[1][3]); }                          \
    } }

__global__ __launch_bounds__(BLOCK, 2)
void router_kernel(const float* __restrict__ x, const float* __restrict__ wde,
                   float* __restrict__ out) {
    __shared__ Smem sm;
    float* smw = sm.buf;

    const int tid  = threadIdx.x;
    const int lane = tid & 63;
    const int w    = tid >> 6;          // wave 0..7
    const int g    = lane >> 4;         // token group 0..3 (also the x XOR key)
    const int el   = lane & 15;         // expert-quad: experts el*4..el*4+3
    const int tl0  = w * 8 + g * NTI;   // lane's first local token
    const int tok0 = blockIdx.x * TOKB;

    // x staging source with storage swizzle: LDS row t, slot sl holds global
    // slot sl ^ k(t), k(t) = (t>>1)&3. For stage lane l covering row
    // 4c+(l>>4): k = (2w + (l>>5)) & 3 (independent of chunk half).
    const int   k     = (2 * w + (lane >> 5)) & 3;
    const char* xsrc0 = (const char*)x
        + ((size_t)(tok0 + (lane >> 4)) * DDIM) * 4
        + (size_t)((((lane & 15) ^ k)) * 16);

    // stage round r: W chunk (linear) + x chunk (swizzled source), 2+2
    // gloads per wave; chunk c = w, w+8 covers LDS bytes [c*1024, c*1024+1024)
    auto stage = [&](int r, int bo2) {
        const char* gw = (const char*)wde + (size_t)r * (CHF * 4);
        char* lw = (char*)(smw + bo2);
        char* lx = (char*)(smw + 2 * CHF + bo2);
        #pragma unroll
        for (int s = 0; s < 2; ++s) {
            const int c = w + 8 * s;
            GLD16(gw + c * 1024 + lane * 16, lw + c * 1024);
            GLD16(xsrc0 + (size_t)c * (4 * DDIM * 4) + (size_t)r * (RD * 4),
                  lx + c * 1024);
        }
    };

    // quarter accumulators: a2 = running quarter, s01 = q0+q1, s23 = q2+q3
    float a2[NTI][4], s01[NTI][4], s23[NTI][4];
    #pragma unroll
    for (int i = 0; i < NTI; ++i)
        #pragma unroll
        for (int e = 0; e < 4; ++e) { a2[i][e] = 0.0f; s01[i][e] = 0.0f; s23[i][e] = 0.0f; }

    // ---- prologue: stage round 0, wait, go ----
    stage(0, 0);
    __builtin_amdgcn_sched_barrier(0);
    RBAR();

    // ---- main loop: 32 rounds of 64 d, one barrier per round ----
    int bo = 0;
    for (int r = 0; r < NR; ++r) {
        if (r + 1 < NR) {
            stage(r + 1, bo ^ CHF);         // async into the other buffers
            __builtin_amdgcn_sched_barrier(0);   // keep gloads at round top
        }
        const float* wl  = smw + bo + el * 4;
        const float* xt0 = smw + 2 * CHF + bo + (w * 8 + g * NTI) * RD;
        #pragma unroll
        for (int jb = 0; jb < JB; ++jb) {
            const float* wj  = wl + jb * 16 * NEXP;
            const float* xj0 = xt0 + jb * 16;
            const float* xj1 = xt0 + RD + jb * 16;
            STEP(0)
            STEP(1)
            STEP(2)
            STEP(3)
        }
        RBAR();
        bo ^= CHF;
        if ((r & 7) == 7) {                 // quarter boundary: fold, re-zero
            const int q = r >> 3;
            #pragma unroll
            for (int i = 0; i < NTI; ++i)
                #pragma unroll
                for (int e = 0; e < 4; ++e) {
                    if (q == 0)      s01[i][e]  = a2[i][e];
                    else if (q == 1) s01[i][e] += a2[i][e];
                    else if (q == 2) s23[i][e]  = a2[i][e];
                    else             s23[i][e] += a2[i][e];
                    a2[i][e] = 0.0f;
                }
        }
    }

    // combine quarters exactly like the validated kernel: (q0+q1)+(q2+q3)
    #pragma unroll
    for (int i = 0; i < NTI; ++i)
        #pragma unroll
        for (int e = 0; e < 4; ++e)
            sm.logit[tl0 + i][el * 4 + e] = s01[i][e] + s23[i][e];
    __syncthreads();

    if (tid < 64) {
        const int tok = tok0 + tid;
        float lg[NEXP];
        #pragma unroll
        for (int e = 0; e < NEXP; ++e) lg[e] = sm.logit[tid][e];

        // softmax over 64 experts (fp32, max-subtracted)
        float m = lg[0];
        #pragma unroll
        for (int e = 1; e < NEXP; ++e) m = fmaxf(m, lg[e]);
        float s = 0.0f;
        #pragma unroll
        for (int e = 0; e < NEXP; ++e) { lg[e] = expf(lg[e] - m); s += lg[e]; }

        // top-8, strict '>' keeps lowest index on ties (lax.top_k semantics)
        unsigned long long chosen = 0ull;
        float wv[8], wi[8];
        #pragma unroll
        for (int kk = 0; kk < 8; ++kk) {
            float best = -1.0f; int bi = 0;
            #pragma unroll
            for (int e = 0; e < NEXP; ++e) {
                bool ok = (((chosen >> e) & 1ull) == 0ull) && (lg[e] > best);
                best = ok ? lg[e] : best;
                bi   = ok ? e : bi;
            }
            chosen |= (1ull << bi);
            wv[kk] = best;
            wi[kk] = (float)bi;
        }

        // second softmax over the 8 selected gating probabilities
        float p0 = wv[0] / s;
        float e2[8]; float s2 = 0.0f;
        #pragma unroll
        for (int kk = 0; kk < 8; ++kk) { e2[kk] = expf(wv[kk] / s - p0); s2 += e2[kk]; }

        float4* ow = (float4*)(out + (size_t)tok * 8);
        ow[0] = make_float4(e2[0]/s2, e2[1]/s2, e2[2]/s2, e2[3]/s2);
        ow[1] = make_float4(e2[4]/s2, e2[5]/s2, e2[6]/s2, e2[7]/s2);
        float4* oi = (float4*)(out + (size_t)NTOK * 8 + (size_t)tok * 8);
        oi[0] = make_float4(wi[0], wi[1], wi[2], wi[3]);
        oi[1] = make_float4(wi[4], wi[5], wi[6], wi[7]);
    }
}

extern "C" void kernel_launch(void* const* d_in, const int* in_sizes, int n_in,
                              void* d_out, int out_size, void* d_ws, size_t ws_size,
                              hipStream_t stream) {
    const float* x   = (const float*)d_in[0];
    const float* wde = (const float*)d_in[1];
    float* out       = (float*)d_out;
    router_kernel<<<dim3(NTOK / TOKB), dim3(BLOCK), 0, stream>>>(x, wde, out);
}